// Round 1
// baseline (306.042 us; speedup 1.0000x reference)
//
#include <hip/hip_runtime.h>
#include <hip/hip_bf16.h>

#define N_NODES 100000
#define N_EDGES 1600000

// ---------- bf16 helpers (manual, bit-level) ----------
__device__ __forceinline__ unsigned short f2bf(float f) {
    unsigned int u = __float_as_uint(f);
    u += 0x7fffu + ((u >> 16) & 1u);   // round-to-nearest-even
    return (unsigned short)(u >> 16);
}
__device__ __forceinline__ float2 bfpair(unsigned int w) {
    // low short -> .x, high short -> .y
    return float2{__uint_as_float(w << 16), __uint_as_float(w & 0xffff0000u)};
}

// ---------------------------------------------------------------------------
// Phase 1: AB[n][0:128]   = x[n] @ W1[:, :128]^T      (A part)
//          AB[n][128:256] = x[n] @ W1[:, 128:]^T      (B part)
// Stored as bf16 in d_ws. NOTE: b1 is NOT added here (it would be added
// twice through A and B); it is applied in phase 2.
//
// Block: 256 threads, 64 nodes x 64 output-cols per block.
// grid = (ceil(N/64), 4): blockIdx.y selects (half of K-concat, half of cols).
// LDS: x tile fp32 [64][132] (pad 132 -> 2-way-free bank pattern on b128),
//      weight tile bf16 [64][132].
// Micro-tile: 4 nodes x 4 cols per thread (cols strided by 16 ->
// conflict-free/broadcast LDS weight reads).
// ---------------------------------------------------------------------------
__global__ __launch_bounds__(256) void precompute_kernel(
    const float* __restrict__ x, const float* __restrict__ W1,
    unsigned short* __restrict__ AB) {
    __shared__ float xs[64 * 132];
    __shared__ unsigned short wl[64 * 132];

    const int tid = threadIdx.x;
    const int qy = blockIdx.y;            // 0..3
    const int n_base = blockIdx.x * 64;
    const int half = qy >> 1;             // which K-half of W1 (A vs B)
    const int jbase = (qy & 1) * 64;      // which 64 output cols of this half

    // ---- stage weights: W1 row (jbase+j), k-slice half*128 + [0,128) -> bf16
    {
        const int j = tid >> 2, q = tid & 3;
        const float4* s4 = reinterpret_cast<const float4*>(
            W1 + (size_t)(jbase + j) * 256 + half * 128 + q * 32);
        unsigned int* d32 =
            reinterpret_cast<unsigned int*>(&wl[j * 132 + q * 32]);
#pragma unroll
        for (int i = 0; i < 8; ++i) {
            float4 w4 = s4[i];
            d32[2 * i + 0] = (unsigned int)f2bf(w4.x) | ((unsigned int)f2bf(w4.y) << 16);
            d32[2 * i + 1] = (unsigned int)f2bf(w4.z) | ((unsigned int)f2bf(w4.w) << 16);
        }
    }
    // ---- stage x tile: 64 rows x 128 fp32, contiguous global, padded LDS
    {
#pragma unroll
        for (int i = 0; i < 8; ++i) {
            int fi = tid + i * 256;       // float4 index 0..2047
            int n = fi >> 5, c4 = fi & 31;
            float4 v = {0.f, 0.f, 0.f, 0.f};
            if (n_base + n < N_NODES)
                v = reinterpret_cast<const float4*>(x)[(size_t)(n_base + n) * 32 + c4];
            *reinterpret_cast<float4*>(&xs[n * 132 + c4 * 4]) = v;
        }
    }
    __syncthreads();

    const int ng = tid >> 4;    // node group 0..15 -> nodes ng*4..+3
    const int cgl = tid & 15;   // col lane -> cols {cgl, cgl+16, cgl+32, cgl+48}
    float acc[4][4] = {};

#pragma unroll 4
    for (int k = 0; k < 128; k += 4) {
        float4 xv[4];
#pragma unroll
        for (int i = 0; i < 4; ++i)
            xv[i] = *reinterpret_cast<const float4*>(&xs[(ng * 4 + i) * 132 + k]);
#pragma unroll
        for (int j = 0; j < 4; ++j) {
            uint2 wz = *reinterpret_cast<const uint2*>(&wl[(cgl + 16 * j) * 132 + k]);
            float2 w01 = bfpair(wz.x);
            float2 w23 = bfpair(wz.y);
#pragma unroll
            for (int i = 0; i < 4; ++i) {
                acc[i][j] = fmaf(xv[i].x, w01.x, acc[i][j]);
                acc[i][j] = fmaf(xv[i].y, w01.y, acc[i][j]);
                acc[i][j] = fmaf(xv[i].z, w23.x, acc[i][j]);
                acc[i][j] = fmaf(xv[i].w, w23.y, acc[i][j]);
            }
        }
    }

    // ---- store: AB col = qy*64 + local col
#pragma unroll
    for (int i = 0; i < 4; ++i) {
        int n = n_base + ng * 4 + i;
        if (n < N_NODES) {
#pragma unroll
            for (int j = 0; j < 4; ++j)
                AB[(size_t)n * 256 + qy * 64 + cgl + 16 * j] = f2bf(acc[i][j]);
        }
    }
}

// ---------------------------------------------------------------------------
// Phase 2: out[e] = W2 . relu(A[u] + B[v] + b1) + b2
// 16 lanes per edge (each lane: 8 features, one 16B bf16x8 load per endpoint),
// 4 edges per wave, grid-stride. Reduction: 4 x shfl_xor within 16-lane group.
// ---------------------------------------------------------------------------
__global__ __launch_bounds__(256) void edge_kernel(
    const long long* __restrict__ ei, const unsigned short* __restrict__ AB,
    const float* __restrict__ b1, const float* __restrict__ W2,
    const float* __restrict__ b2, float* __restrict__ out) {
    const int lane = threadIdx.x & 63;
    const int sub = lane >> 4;   // which of 4 edges in this wave-iter
    const int sl = lane & 15;    // feature sub-lane
    const int k0 = sl * 8;

    float b1v[8], w2v[8];
#pragma unroll
    for (int j = 0; j < 8; ++j) { b1v[j] = b1[k0 + j]; w2v[j] = W2[k0 + j]; }
    const float bias2 = b2[0];

    // Robustness: detect whether edge_index is really int64 (declared) or
    // int32 (if harness ran without x64). Under int64, high words of the
    // first 64 entries are all 0 (values < 100000). Under int32 the "high
    // words" are random indices -> ballot virtually never all-zero.
    const unsigned int hi = reinterpret_cast<const unsigned int*>(ei)[2 * lane + 1];
    const bool is64 = (__ballot(hi != 0) == 0ull);

    const int wid = (int)(((unsigned)(blockIdx.x * blockDim.x + threadIdx.x)) >> 6);
    const int nwaves = (int)(((unsigned)(gridDim.x * blockDim.x)) >> 6);

    for (int base = wid * 4; base < N_EDGES; base += nwaves * 4) {
        const int e = base + sub;   // N_EDGES % 4 == 0 -> always in range
        int u, v;
        if (is64) {
            u = (int)ei[e];
            v = (int)ei[N_EDGES + e];
        } else {
            const int* e32 = reinterpret_cast<const int*>(ei);
            u = e32[e];
            v = e32[N_EDGES + e];
        }
        uint4 ua = *reinterpret_cast<const uint4*>(AB + (size_t)u * 256 + k0);
        uint4 vb = *reinterpret_cast<const uint4*>(AB + (size_t)v * 256 + 128 + k0);
        unsigned int uaa[4] = {ua.x, ua.y, ua.z, ua.w};
        unsigned int vba[4] = {vb.x, vb.y, vb.z, vb.w};
        float p = 0.f;
#pragma unroll
        for (int q = 0; q < 4; ++q) {
            float2 a = bfpair(uaa[q]);
            float2 b = bfpair(vba[q]);
            float s0 = fmaxf(a.x + b.x + b1v[2 * q], 0.f);
            float s1 = fmaxf(a.y + b.y + b1v[2 * q + 1], 0.f);
            p = fmaf(s0, w2v[2 * q], p);
            p = fmaf(s1, w2v[2 * q + 1], p);
        }
        p += __shfl_xor(p, 1);
        p += __shfl_xor(p, 2);
        p += __shfl_xor(p, 4);
        p += __shfl_xor(p, 8);
        if (sl == 0) out[e] = p + bias2;
    }
}

extern "C" void kernel_launch(void* const* d_in, const int* in_sizes, int n_in,
                              void* d_out, int out_size, void* d_ws, size_t ws_size,
                              hipStream_t stream) {
    const float* x = (const float*)d_in[0];
    const long long* ei = (const long long*)d_in[1];
    const float* W1 = (const float*)d_in[2];
    const float* b1 = (const float*)d_in[3];
    const float* W2 = (const float*)d_in[4];
    const float* b2 = (const float*)d_in[5];
    float* out = (float*)d_out;
    unsigned short* AB = (unsigned short*)d_ws;   // 100000*256*2 = 51.2 MB

    dim3 g1((N_NODES + 63) / 64, 4);
    precompute_kernel<<<g1, 256, 0, stream>>>(x, W1, AB);
    edge_kernel<<<2048, 256, 0, stream>>>(ei, AB, b1, W2, b2, out);
}

// Round 2
// 234.382 us; speedup vs baseline: 1.3057x; 1.3057x over previous
//
#include <hip/hip_runtime.h>
#include <hip/hip_bf16.h>

#define N_NODES 100000
#define N_EDGES 1600000

typedef __attribute__((ext_vector_type(8))) short short8v;   // 8 bf16 = 4 VGPRs
typedef __attribute__((ext_vector_type(4))) float float4v;   // MFMA C/D

// ---------- bf16 helpers (manual, bit-level) ----------
__device__ __forceinline__ unsigned short f2bf(float f) {
    unsigned int u = __float_as_uint(f);
    u += 0x7fffu + ((u >> 16) & 1u);   // round-to-nearest-even
    return (unsigned short)(u >> 16);
}
__device__ __forceinline__ unsigned int pack2bf(float a, float b) {
    return (unsigned int)f2bf(a) | ((unsigned int)f2bf(b) << 16);
}
__device__ __forceinline__ float2 bfpair(unsigned int w) {
    return float2{__uint_as_float(w << 16), __uint_as_float(w & 0xffff0000u)};
}

// ---------------------------------------------------------------------------
// Phase 1 (MFMA): AB = x @ Wbig^T, where Wbig[j][k] = W1[j&127][(j>>7)*128+k].
//   AB[n][0:128]   = x[n] @ W1[:, :128]^T   (A part)
//   AB[n][128:256] = x[n] @ W1[:, 128:]^T   (B part)
// b1 is NOT added here (applied once in phase 2).
//
// Block: 256 threads (4 waves). Tile: 64 nodes x 128 cols; blockIdx.y picks
// the col half (= which K-half of W1). LDS (stride 136 shorts = 272 B ->
// 2-way bank aliasing on b128 frag reads, free per m136):
//   xlds 64x136 bf16 = 17.4 KB, wlds 128x136 bf16 = 34.8 KB  (52 KB -> 3 blk/CU)
// Wave w computes cols [w*32, w*32+32): 4 m-tiles x 2 n-tiles of 16x16, K=128
// as 4 steps of mfma_f32_16x16x32_bf16.
// ---------------------------------------------------------------------------
__global__ __launch_bounds__(256) void precompute_kernel(
    const float* __restrict__ x, const float* __restrict__ W1,
    unsigned short* __restrict__ AB) {
    __shared__ unsigned short xlds[64 * 136];
    __shared__ unsigned short wlds[128 * 136];

    const int tid = threadIdx.x;
    const int n0 = blockIdx.x * 64;
    const int by = blockIdx.y;            // 0: A-half, 1: B-half
    const int jbase = by * 128;           // global AB col base

    // ---- stage W half: rows jl=0..127, W1[jl][by*128 + 0..127] -> bf16
    {
#pragma unroll
        for (int i = 0; i < 16; ++i) {
            int fi = tid + i * 256;           // float4 idx 0..4095
            int jl = fi >> 5, c4 = fi & 31;   // row, float4-in-row
            float4 w4 = reinterpret_cast<const float4*>(W1)[(size_t)jl * 64 + by * 32 + c4];
            unsigned int* d = reinterpret_cast<unsigned int*>(&wlds[jl * 136 + c4 * 4]);
            d[0] = pack2bf(w4.x, w4.y);
            d[1] = pack2bf(w4.z, w4.w);
        }
    }
    // ---- stage x tile: 64 rows x 128 fp32 -> bf16
    {
#pragma unroll
        for (int i = 0; i < 8; ++i) {
            int fi = tid + i * 256;           // float4 idx 0..2047
            int n = fi >> 5, c4 = fi & 31;
            float4 v = {0.f, 0.f, 0.f, 0.f};
            if (n0 + n < N_NODES)
                v = reinterpret_cast<const float4*>(x)[(size_t)(n0 + n) * 32 + c4];
            unsigned int* d = reinterpret_cast<unsigned int*>(&xlds[n * 136 + c4 * 4]);
            d[0] = pack2bf(v.x, v.y);
            d[1] = pack2bf(v.z, v.w);
        }
    }
    __syncthreads();

    const int wave = tid >> 6;
    const int lane = tid & 63;
    const int quad = lane >> 4;
    const int l15 = lane & 15;

    float4v acc[4][2];
#pragma unroll
    for (int i = 0; i < 4; ++i)
#pragma unroll
        for (int j = 0; j < 2; ++j) acc[i][j] = float4v{0.f, 0.f, 0.f, 0.f};

#pragma unroll
    for (int s = 0; s < 4; ++s) {
        const int k0 = s * 32 + quad * 8;
        short8v a[4], b[2];
#pragma unroll
        for (int i = 0; i < 4; ++i)
            a[i] = *reinterpret_cast<const short8v*>(&xlds[(i * 16 + l15) * 136 + k0]);
#pragma unroll
        for (int j = 0; j < 2; ++j)
            b[j] = *reinterpret_cast<const short8v*>(&wlds[(wave * 32 + j * 16 + l15) * 136 + k0]);
#pragma unroll
        for (int i = 0; i < 4; ++i)
#pragma unroll
            for (int j = 0; j < 2; ++j)
                acc[i][j] = __builtin_amdgcn_mfma_f32_16x16x32_bf16(a[i], b[j], acc[i][j], 0, 0, 0);
    }

    // ---- epilogue: C/D layout col=lane&15, row=quad*4+r
#pragma unroll
    for (int i = 0; i < 4; ++i) {
        const int rowb = i * 16 + quad * 4;
#pragma unroll
        for (int r = 0; r < 4; ++r) {
            const int n = n0 + rowb + r;
            if (n < N_NODES) {
#pragma unroll
                for (int j = 0; j < 2; ++j) {
                    const int col = jbase + wave * 32 + j * 16 + l15;
                    AB[(size_t)n * 256 + col] = f2bf(acc[i][j][r]);
                }
            }
        }
    }
}

// ---------------------------------------------------------------------------
// Phase 2: out[e] = W2 . relu(A[u] + B[v] + b1) + b2
// 16 lanes per edge (one 16B bf16x8 load per endpoint per lane),
// 4 edges per wave, grid-stride. Reduction: 4 x shfl_xor within 16-lane group.
// ---------------------------------------------------------------------------
__global__ __launch_bounds__(256) void edge_kernel(
    const long long* __restrict__ ei, const unsigned short* __restrict__ AB,
    const float* __restrict__ b1, const float* __restrict__ W2,
    const float* __restrict__ b2, float* __restrict__ out) {
    const int lane = threadIdx.x & 63;
    const int sub = lane >> 4;   // which of 4 edges in this wave-iter
    const int sl = lane & 15;    // feature sub-lane
    const int k0 = sl * 8;

    float b1v[8], w2v[8];
#pragma unroll
    for (int j = 0; j < 8; ++j) { b1v[j] = b1[k0 + j]; w2v[j] = W2[k0 + j]; }
    const float bias2 = b2[0];

    // Robustness: detect int64 vs int32 edge_index (declared int64; values
    // < 100000 so high words are all zero iff truly int64).
    const unsigned int hi = reinterpret_cast<const unsigned int*>(ei)[2 * lane + 1];
    const bool is64 = (__ballot(hi != 0) == 0ull);

    const int wid = (int)(((unsigned)(blockIdx.x * blockDim.x + threadIdx.x)) >> 6);
    const int nwaves = (int)(((unsigned)(gridDim.x * blockDim.x)) >> 6);

    for (int base = wid * 4; base < N_EDGES; base += nwaves * 4) {
        const int e = base + sub;   // N_EDGES % 4 == 0 -> always in range
        int u, v;
        if (is64) {
            u = (int)ei[e];
            v = (int)ei[N_EDGES + e];
        } else {
            const int* e32 = reinterpret_cast<const int*>(ei);
            u = e32[e];
            v = e32[N_EDGES + e];
        }
        uint4 ua = *reinterpret_cast<const uint4*>(AB + (size_t)u * 256 + k0);
        uint4 vb = *reinterpret_cast<const uint4*>(AB + (size_t)v * 256 + 128 + k0);
        unsigned int uaa[4] = {ua.x, ua.y, ua.z, ua.w};
        unsigned int vba[4] = {vb.x, vb.y, vb.z, vb.w};
        float p = 0.f;
#pragma unroll
        for (int q = 0; q < 4; ++q) {
            float2 a = bfpair(uaa[q]);
            float2 b = bfpair(vba[q]);
            float s0 = fmaxf(a.x + b.x + b1v[2 * q], 0.f);
            float s1 = fmaxf(a.y + b.y + b1v[2 * q + 1], 0.f);
            p = fmaf(s0, w2v[2 * q], p);
            p = fmaf(s1, w2v[2 * q + 1], p);
        }
        p += __shfl_xor(p, 1);
        p += __shfl_xor(p, 2);
        p += __shfl_xor(p, 4);
        p += __shfl_xor(p, 8);
        if (sl == 0) out[e] = p + bias2;
    }
}

extern "C" void kernel_launch(void* const* d_in, const int* in_sizes, int n_in,
                              void* d_out, int out_size, void* d_ws, size_t ws_size,
                              hipStream_t stream) {
    const float* x = (const float*)d_in[0];
    const long long* ei = (const long long*)d_in[1];
    const float* W1 = (const float*)d_in[2];
    const float* b1 = (const float*)d_in[3];
    const float* W2 = (const float*)d_in[4];
    const float* b2 = (const float*)d_in[5];
    float* out = (float*)d_out;
    unsigned short* AB = (unsigned short*)d_ws;   // 100000*256*2 = 51.2 MB

    dim3 g1((N_NODES + 63) / 64, 2);
    precompute_kernel<<<g1, 256, 0, stream>>>(x, W1, AB);
    edge_kernel<<<2048, 256, 0, stream>>>(ei, AB, b1, W2, b2, out);
}